// Round 2
// 538.447 us; speedup vs baseline: 1.0540x; 1.0540x over previous
//
#include <hip/hip_runtime.h>
#include <cstdint>

typedef unsigned short u16;
typedef __attribute__((ext_vector_type(8))) __bf16 bf16x8;
typedef __attribute__((ext_vector_type(4))) float f32x4;

#define M_DIM 8192
#define N_DIM 4096
#define K_DIM 4096

#define CVT_X_BLOCKS 16384   // (M*K)/(256*8)
#define CVT_W_BLOCKS 4096    // (K/64)*(N/64)

// round-to-nearest-even f32 -> bf16 (inputs are Gaussian; no NaN handling needed)
__device__ __forceinline__ u16 f2bf(float f) {
    union { float f; uint32_t u; } v; v.f = f;
    uint32_t u = v.u;
    u += 0x7FFFu + ((u >> 16) & 1u);
    return (u16)(u >> 16);
}

// ---------------- merged converter: one launch for both inputs ----------------
// blocks [0, CVT_X_BLOCKS): x f32 (M,K) -> bf16 (M,K), streaming
// blocks [CVT_X_BLOCKS, +CVT_W_BLOCKS): w f32 (K,N) -> bf16 transposed (N,K), LDS tiled
__global__ __launch_bounds__(256) void cvt_kernel(const float* __restrict__ x,
                                                  const float* __restrict__ w,
                                                  u16* __restrict__ xb,
                                                  u16* __restrict__ wt) {
    const int t = threadIdx.x;
    if (blockIdx.x < CVT_X_BLOCKS) {
        size_t i = ((size_t)blockIdx.x * 256 + t) * 8;
        const float4* p = (const float4*)(x + i);
        float4 v0 = p[0], v1 = p[1];
        uint32_t o0 = (uint32_t)f2bf(v0.x) | ((uint32_t)f2bf(v0.y) << 16);
        uint32_t o1 = (uint32_t)f2bf(v0.z) | ((uint32_t)f2bf(v0.w) << 16);
        uint32_t o2 = (uint32_t)f2bf(v1.x) | ((uint32_t)f2bf(v1.y) << 16);
        uint32_t o3 = (uint32_t)f2bf(v1.z) | ((uint32_t)f2bf(v1.w) << 16);
        uint4 o; o.x = o0; o.y = o1; o.z = o2; o.w = o3;
        *(uint4*)(xb + i) = o;
    } else {
        __shared__ u16 lds[64 * 68];   // stride 68: keeps 8B-aligned b64 writes
        const int bid = blockIdx.x - CVT_X_BLOCKS;
        const int k0 = (bid & 63) * 64;   // k tile origin (K/64 = 64 tiles)
        const int n0 = (bid >> 6) * 64;   // n tile origin
#pragma unroll
        for (int i = 0; i < 4; ++i) {
            int idx = i * 256 + t;
            int r = idx >> 4;            // local k row
            int c4 = (idx & 15) * 4;     // local n (group of 4)
            float4 v = *(const float4*)&w[(size_t)(k0 + r) * N_DIM + n0 + c4];
            uint2 o;
            o.x = (uint32_t)f2bf(v.x) | ((uint32_t)f2bf(v.y) << 16);
            o.y = (uint32_t)f2bf(v.z) | ((uint32_t)f2bf(v.w) << 16);
            *(uint2*)&lds[r * 68 + c4] = o;
        }
        __syncthreads();
#pragma unroll
        for (int i = 0; i < 4; ++i) {
            int idx = i * 256 + t;
            int rn  = idx >> 4;          // local n
            int ck  = (idx & 15) * 4;    // local k (group of 4)
            uint2 o;
            o.x = (uint32_t)lds[(ck + 0) * 68 + rn] | ((uint32_t)lds[(ck + 1) * 68 + rn] << 16);
            o.y = (uint32_t)lds[(ck + 2) * 68 + rn] | ((uint32_t)lds[(ck + 3) * 68 + rn] << 16);
            *(uint2*)&wt[(size_t)(n0 + rn) * K_DIM + k0 + ck] = o;
        }
    }
}

// ---------------- GEMM: C = A(M,K) @ Bt(N,K)^T + bias ----------------
// 256x256 tile, BK=64 (2 k-halves of 32), 8 waves (2M x 4N, 128x64 per wave),
// double-buffered LDS, phase-interleaved schedule with counted vmcnt(4)
// (never drains to 0 in the main loop) + raw s_barrier + setprio around MFMA.
//
// LDS k-chunk XOR swizzle (round-0-proven, 0 conflicts): logical 16B chunk q of
// row r lives at slot q ^ ((r>>1)&3). Applied by pre-swizzling the GLOBAL source
// k-offset (LDS dest stays linear — global_load_lds requires it) and XOR-ing the
// read-side slot. Fragment row-bases are multiples of 16 -> read swizzle uniform.
//
// Wait ledger (2 loads per STAGE_* call; 8 gload_lds per K-tile per thread):
//   entry to tile t:  outstanding = t.kh1 (4)
//   P1: issue t+1.kh0A   P2: issue t+1.kh0B  -> vmcnt(4) proves t.kh1 landed
//   P3: issue t+1.kh1A   P4: issue t+1.kh1B  -> vmcnt(4) proves t+1.kh0 landed
// Every stage-issue is >=1 barrier after the last ds_read of its target region,
// and that ds_read's lgkmcnt-completion precedes its wave's barrier arrival.
typedef const uint32_t __attribute__((address_space(1)))* gp_t;
typedef uint32_t __attribute__((address_space(3)))* lp_t;

#define BK 64
#define NTILES (K_DIM / BK)            // 64
#define TN_TILES (N_DIM / 256)         // 16
#define NWG ((M_DIM / 256) * TN_TILES) // 512

__global__ __launch_bounds__(512, 2) void gemm_kernel(const u16* __restrict__ A,
                                                      const u16* __restrict__ Bt,
                                                      const float* __restrict__ bias,
                                                      float* __restrict__ C) {
    // [buf][khalf][row][k32]; 64B row stride; XOR chunk swizzle -> 2-way (free) banks
    __shared__ u16 As[2][2][256][32];   // 64 KB
    __shared__ u16 Bs[2][2][256][32];   // 64 KB

    const int t    = threadIdx.x;
    const int lane = t & 63;
    const int l16  = lane & 15;
    const int quad = lane >> 4;
    const int wave = t >> 6;       // 0..7
    const int wr   = wave >> 2;    // 0..1 (M): rows wr*128..+128
    const int wc   = wave & 3;     // 0..3 (N): cols wc*64..+64

    // XCD-aware bijective swizzle (NWG % 8 == 0): same-XCD blocks share A-panel
    const int bid = blockIdx.x;
    const int wg  = (bid & 7) * (NWG >> 3) + (bid >> 3);
    const int bm  = (wg / TN_TILES) * 256;
    const int bn  = (wg % TN_TILES) * 256;

    // staging chunks: thread owns chunks {t, t+512} of each 16KB k-half region.
    // chunk c -> LDS byte 16*c -> row = c>>2, slot = c&3 (wave-linear dest);
    // fetch global k-chunk (slot ^ ((row>>1)&3)) so LDS slot holds swizzled data.
    const int rC0 = t >> 2;
    const int rC1 = rC0 + 128;                        // (t+512)>>2
    const int kcS = ((t & 3) ^ ((rC0 >> 1) & 3)) * 8; // same for rC1 (+128 rows)
    const u16* a0 = A  + (size_t)(bm + rC0) * K_DIM + kcS;
    const u16* a1 = A  + (size_t)(bm + rC1) * K_DIM + kcS;
    const u16* b0 = Bt + (size_t)(bn + rC0) * K_DIM + kcS;
    const u16* b1 = Bt + (size_t)(bn + rC1) * K_DIM + kcS;

    // read-side swizzled slot offset (uniform over i/j: row bases are mult of 16)
    const int sw8 = (quad ^ ((l16 >> 1) & 3)) * 8;

    f32x4 acc[8][4] = {};
    bf16x8 af[4], bf[4];

#define STAGE_A(buf, kh, kk) do {                                                                   \
        __builtin_amdgcn_global_load_lds((gp_t)(a0 + (kk) + (kh) * 32), (lp_t)&As[buf][kh][rC0][(t & 3) * 8], 16, 0, 0); \
        __builtin_amdgcn_global_load_lds((gp_t)(a1 + (kk) + (kh) * 32), (lp_t)&As[buf][kh][rC1][(t & 3) * 8], 16, 0, 0); \
    } while (0)
#define STAGE_B(buf, kh, kk) do {                                                                   \
        __builtin_amdgcn_global_load_lds((gp_t)(b0 + (kk) + (kh) * 32), (lp_t)&Bs[buf][kh][rC0][(t & 3) * 8], 16, 0, 0); \
        __builtin_amdgcn_global_load_lds((gp_t)(b1 + (kk) + (kh) * 32), (lp_t)&Bs[buf][kh][rC1][(t & 3) * 8], 16, 0, 0); \
    } while (0)
#define LDA(buf, kh, mbase)                                                                \
    _Pragma("unroll")                                                                      \
    for (int i = 0; i < 4; ++i)                                                            \
        af[i] = *(const bf16x8*)&As[buf][kh][wr * 128 + ((mbase) + i) * 16 + l16][sw8]
#define LDB(buf, kh)                                                                       \
    _Pragma("unroll")                                                                      \
    for (int j = 0; j < 4; ++j)                                                            \
        bf[j] = *(const bf16x8*)&Bs[buf][kh][wc * 64 + j * 16 + l16][sw8]
#define MFMA16(mbase)                                                                      \
    __builtin_amdgcn_s_setprio(1);                                                         \
    _Pragma("unroll")                                                                      \
    for (int i = 0; i < 4; ++i)                                                            \
        _Pragma("unroll")                                                                  \
        for (int j = 0; j < 4; ++j)                                                        \
            acc[(mbase) + i][j] =                                                          \
                __builtin_amdgcn_mfma_f32_16x16x32_bf16(af[i], bf[j], acc[(mbase) + i][j], 0, 0, 0); \
    __builtin_amdgcn_s_setprio(0)
#define FENCE() asm volatile("" ::: "memory")

    // prologue: stage tile 0 fully into buf0; wait for its kh0 (oldest 4 of 8)
    STAGE_A(0, 0, 0); STAGE_B(0, 0, 0);
    STAGE_A(0, 1, 0); STAGE_B(0, 1, 0);
    asm volatile("s_waitcnt vmcnt(4)" ::: "memory");
    __builtin_amdgcn_s_barrier();
    FENCE();

#pragma unroll 2
    for (int tt = 0; tt < NTILES; ++tt) {
        const int nb = tt & 1;
        const int pb = nb ^ 1;
        const int kn = (tt + 1 < NTILES) ? (tt + 1) * BK : 0;  // clamped dummy tail

        // ---- P1: kh0, m-frags 0-3 (B-frags read once, reused in P2) ----
        STAGE_A(pb, 0, kn);
        LDB(nb, 0);
        LDA(nb, 0, 0);
        MFMA16(0);
        // ---- P2: kh0, m-frags 4-7 ----
        STAGE_B(pb, 0, kn);
        LDA(nb, 0, 4);
        MFMA16(4);

        asm volatile("s_waitcnt vmcnt(4)" ::: "memory");  // tile t kh1 landed
        __builtin_amdgcn_s_barrier();
        FENCE();

        // ---- P3: kh1, m-frags 0-3 ----
        STAGE_A(pb, 1, kn);
        LDB(nb, 1);
        LDA(nb, 1, 0);
        MFMA16(0);
        // ---- P4: kh1, m-frags 4-7 ----
        STAGE_B(pb, 1, kn);
        LDA(nb, 1, 4);
        MFMA16(4);

        asm volatile("s_waitcnt vmcnt(4)" ::: "memory");  // tile t+1 kh0 landed
        __builtin_amdgcn_s_barrier();
        FENCE();
    }

    // epilogue: C/D layout col=lane&15, row=quad*4+r (m89/m91-verified); fuse bias
#pragma unroll
    for (int j = 0; j < 4; ++j) {
        const int col = bn + wc * 64 + j * 16 + l16;
        const float bv = bias[col];
#pragma unroll
        for (int i = 0; i < 8; ++i) {
            const int row = bm + wr * 128 + i * 16 + quad * 4;
#pragma unroll
            for (int r = 0; r < 4; ++r)
                C[(size_t)(row + r) * N_DIM + col] = acc[i][j][r] + bv;
        }
    }
#undef STAGE_A
#undef STAGE_B
#undef LDA
#undef LDB
#undef MFMA16
#undef FENCE
}

extern "C" void kernel_launch(void* const* d_in, const int* in_sizes, int n_in,
                              void* d_out, int out_size, void* d_ws, size_t ws_size,
                              hipStream_t stream) {
    const float* x = (const float*)d_in[0];   // (8192, 4096) f32
    const float* w = (const float*)d_in[1];   // (4096, 4096) f32
    const float* b = (const float*)d_in[2];   // (4096,)      f32
    float* out = (float*)d_out;               // (8192, 4096) f32

    // workspace: xb (M*K bf16, 64MB) + wt (N*K bf16, 32MB) = 96MB
    u16* xb = (u16*)d_ws;
    u16* wt = xb + (size_t)M_DIM * K_DIM;

    cvt_kernel<<<CVT_X_BLOCKS + CVT_W_BLOCKS, 256, 0, stream>>>(x, w, xb, wt);
    gemm_kernel<<<dim3(NWG), 512, 0, stream>>>(xb, wt, b, out);
}